// Round 2
// baseline (369.466 us; speedup 1.0000x reference)
//
#include <hip/hip_runtime.h>
#include <math.h>

// Problem constants (from reference setup_inputs)
constexpr int B_ = 2048, C_ = 3, T_ = 300, J_ = 25;
constexpr int SLAB = T_ * J_;   // 7500 floats per (b,c) slab, contiguous
constexpr int NBC  = B_ * C_;   // 6144 slabs

// One block per (b,c) slab. 250 active threads, float4 loads, per-iteration
// stride 1000 elements (== 0 mod 25) so each thread's 4 lanes keep FIXED
// column indices j = (4*tid+k) % 25 for the entire slab -> smooth column
// sums live in 4 registers per thread, no LDS staging, no dynamic indexing.
__global__ __launch_bounds__(256) void fused_kernel(
    const float* __restrict__ gin, const float* __restrict__ gtg,
    float* __restrict__ rec_part, float* __restrict__ sm_part) {
  __shared__ float s_col[J_];   // column sums sx - st
  __shared__ float s_red[4];

  const int tid  = threadIdx.x;
  const int lane = tid & 63;
  const int wave = tid >> 6;

  if (tid < J_) s_col[tid] = 0.f;
  __syncthreads();  // init visible before the end-of-loop atomics

  const size_t base = (size_t)blockIdx.x * SLAB;  // slab start, 16B-aligned
  const float* in = gin + base;
  const float* tg = gtg + base;

  float rec = 0.f;
  float p0 = 0.f, p1 = 0.f, p2 = 0.f, p3 = 0.f;
  const int e0 = tid * 4;

  if (tid < 250) {
    // Element (t,j) contributes to sx: +x if t<T-1 (e<7475), -x^2 if t>0 (e>=25).
    // p accumulates (x-contrib) - (y-contrib):
    //   lin  = x - y            = d          (if e < 7475)
    //   quad = -(x^2 - y^2)     = -d*(x+y)   (if e >= 25)
    #pragma unroll
    for (int it = 0; it < 8; ++it) {
      const int e = it * 1000 + e0;  // 1000 % 25 == 0 -> fixed j per k
      if (e < SLAB) {                // only trims it==7, tid>=125
        const float4 x = *(const float4*)(in + e);
        const float4 y = *(const float4*)(tg + e);
        { float d = x.x - y.x, s = x.x + y.x; rec += d * d;
          p0 += (e     < 7475 ? d : 0.f) - (e     >= 25 ? d * s : 0.f); }
        { float d = x.y - y.y, s = x.y + y.y; rec += d * d;
          p1 += (e + 1 < 7475 ? d : 0.f) - (e + 1 >= 25 ? d * s : 0.f); }
        { float d = x.z - y.z, s = x.z + y.z; rec += d * d;
          p2 += (e + 2 < 7475 ? d : 0.f) - (e + 2 >= 25 ? d * s : 0.f); }
        { float d = x.w - y.w, s = x.w + y.w; rec += d * d;
          p3 += (e + 3 < 7475 ? d : 0.f) - (e + 3 >= 25 ? d * s : 0.f); }
      }
    }
    const int j0 = (tid * 4) % 25;
    atomicAdd(&s_col[j0],            p0);
    atomicAdd(&s_col[(j0 + 1) % 25], p1);
    atomicAdd(&s_col[(j0 + 2) % 25], p2);
    atomicAdd(&s_col[(j0 + 3) % 25], p3);
  }

  // rec: wave shuffle reduce -> LDS -> block total
  #pragma unroll
  for (int off = 32; off > 0; off >>= 1) rec += __shfl_down(rec, off, 64);
  if (lane == 0) s_red[wave] = rec;
  __syncthreads();

  if (wave == 0) {
    float aval = (lane < J_ - 1) ? fabsf(s_col[lane]) : 0.f;  // j < 24 only
    #pragma unroll
    for (int off = 32; off > 0; off >>= 1) aval += __shfl_down(aval, off, 64);
    if (lane == 0) {
      rec_part[blockIdx.x] = s_red[0] + s_red[1] + s_red[2] + s_red[3];
      sm_part[blockIdx.x]  = sqrtf(aval);
    }
  }
}

__global__ __launch_bounds__(256) void finalize_kernel(
    const float* __restrict__ rec_part, const float* __restrict__ sm_part,
    float* __restrict__ out) {
  const int tid  = threadIdx.x;
  const int lane = tid & 63;
  const int wave = tid >> 6;
  double r = 0.0, s = 0.0;
  for (int i = tid; i < NBC; i += 256) {
    r += (double)rec_part[i];
    s += (double)sm_part[i];
  }
  #pragma unroll
  for (int off = 32; off > 0; off >>= 1) {
    r += __shfl_down(r, off, 64);
    s += __shfl_down(s, off, 64);
  }
  __shared__ double sr[4], ss[4];
  if (lane == 0) { sr[wave] = r; ss[wave] = s; }
  __syncthreads();
  if (tid == 0) {
    const double rt = sr[0] + sr[1] + sr[2] + sr[3];
    const double st = ss[0] + ss[1] + ss[2] + ss[3];
    const double loss_rec    = rt / (double)((long long)B_ * C_ * T_ * J_);
    const double loss_smooth = (st / (double)NBC) / (double)(J_ * T_);
    out[0] = (float)(2.0 * loss_rec + 3.0 * loss_smooth);
  }
}

extern "C" void kernel_launch(void* const* d_in, const int* in_sizes, int n_in,
                              void* d_out, int out_size, void* d_ws, size_t ws_size,
                              hipStream_t stream) {
  const float* in = (const float*)d_in[0];
  const float* tg = (const float*)d_in[1];
  float* rec_part = (float*)d_ws;       // 6144 floats
  float* sm_part  = rec_part + NBC;     // 6144 floats (48 KB total)
  fused_kernel<<<NBC, 256, 0, stream>>>(in, tg, rec_part, sm_part);
  finalize_kernel<<<1, 256, 0, stream>>>(rec_part, sm_part, (float*)d_out);
}